// Round 2
// baseline (412.460 us; speedup 1.0000x reference)
//
#include <hip/hip_runtime.h>

// One workgroup = ONE WAVE (64 threads) per batch element b.
// Thread t owns hidden neurons h=t and h=t+64. The 20-substep loop is
// entirely register/shuffle-based: no LDS, no barriers (workgroup==wave, so
// __syncthreads() compiles to waitcnt only). Output neurons (G=4) are
// computed redundantly in all lanes after a 4-way shuffle butterfly.
// LDS holds W_in (8KB) + W_out (2KB) staged once, reused by the update tail.

namespace {

constexpr int F = 16;
constexpr int H = 128;
constexpr int G = 4;
constexpr int S = 20;

__device__ __forceinline__ float clip3(float x) {
    return fminf(fmaxf(x, -3.0f), 3.0f);
}

__global__ __launch_bounds__(64)
void spiking_critic_kernel(
    const float* __restrict__ energy,
    const float* __restrict__ threat,
    const float* __restrict__ food_visible,
    const int*   __restrict__ goal,
    const int*   __restrict__ prev_goal,
    const float* __restrict__ DA,
    const float* __restrict__ NA,
    const float* __restrict__ reward,
    const float* __restrict__ cls_probs,
    const float* __restrict__ W_in_w,
    const float* __restrict__ W_in_b,
    const float* __restrict__ W_out_w,
    const float* __restrict__ W_out_b,
    const float* __restrict__ hv_in,
    const float* __restrict__ hu_in,
    const float* __restrict__ hrate_in,
    const float* __restrict__ vv_in,
    const float* __restrict__ vu_in,
    const float* __restrict__ vrate_in,
    const float* __restrict__ elig_in,
    const float* __restrict__ elig_out,
    const float* __restrict__ prev_values,
    const float* __restrict__ prev_features,
    const float* __restrict__ noise,
    float* __restrict__ out_values,
    float* __restrict__ out_td,
    float* __restrict__ out_hidden,
    float* __restrict__ out_Win,
    float* __restrict__ out_Wout,
    float* __restrict__ out_ein,
    float* __restrict__ out_eout,
    int nB)
{
    const int b = blockIdx.x;
    const int t = threadIdx.x;          // 0..63

    __shared__ __align__(16) float w_in_lds[H * F];   // 8 KB
    __shared__ __align__(16) float w_out_lds[G * H];  // 2 KB
    __shared__ __align__(16) float hrate_lds[H];
    __shared__ __align__(16) float feat[F];
    __shared__ __align__(16) float pf_lds[F];

    // ---- stage weights into LDS (coalesced float4) ----
    const float4* wi4 = (const float4*)(W_in_w + (size_t)b * (H * F));
    float4* wl4 = (float4*)w_in_lds;
    #pragma unroll
    for (int k = 0; k < 8; ++k) wl4[t + 64 * k] = wi4[t + 64 * k];
    const float4* wog = (const float4*)(W_out_w + (size_t)b * (G * H));
    float4* wo4 = (float4*)w_out_lds;
    #pragma unroll
    for (int k = 0; k < 2; ++k) wo4[t + 64 * k] = wog[t + 64 * k];

    if (t < F) pf_lds[t] = prev_features[(size_t)b * F + t];

    // ---- features (lanes 0..15, one feature each) ----
    if (t < F) {
        float e = energy[b];
        float v;
        if      (t == 0)  v = e / 100.0f;
        else if (t == 1)  v = threat[b];
        else if (t == 2)  v = food_visible[b];
        else if (t == 3)  v = 1.0f - e / 100.0f;
        else if (t < 8)   v = (goal[b] == (t - 4)) ? 1.0f : 0.0f;
        else if (t < 13)  v = cls_probs[(size_t)b * 5 + (t - 8)];
        else if (t == 13) v = DA[b];
        else if (t == 14) v = NA[b];
        else              v = fmaxf(0.0f, 0.5f - e / 100.0f);
        feat[t] = v;
    }
    __syncthreads();   // single wave: compiles to lgkmcnt wait only

    // ---- I_in for h0=t and h1=t+64, then mean-|.| normalization ----
    float Iraw0 = W_in_b[(size_t)b * H + t];
    float Iraw1 = W_in_b[(size_t)b * H + t + 64];
    #pragma unroll
    for (int j = 0; j < 4; ++j) {
        float4 w0 = ((const float4*)w_in_lds)[t * 4 + j];
        float4 w1 = ((const float4*)w_in_lds)[(t + 64) * 4 + j];
        float fx = feat[4 * j + 0], fy = feat[4 * j + 1];
        float fz = feat[4 * j + 2], fw = feat[4 * j + 3];
        Iraw0 += w0.x * fx + w0.y * fy + w0.z * fz + w0.w * fw;
        Iraw1 += w1.x * fx + w1.y * fy + w1.z * fz + w1.w * fw;
    }
    float a = fabsf(Iraw0) + fabsf(Iraw1);
    #pragma unroll
    for (int m = 32; m >= 1; m >>= 1) a += __shfl_xor(a, m, 64);
    float inorm = 5.0f / (a * (1.0f / 128.0f) + 1e-8f);
    float Iin0 = Iraw0 * inorm;
    float Iin1 = Iraw1 * inorm;

    // ---- per-lane W_out columns (w[g][t], w[g][t+64]) ----
    float wc0[G], wc1[G], wob[G];
    #pragma unroll
    for (int g = 0; g < G; ++g) {
        wc0[g] = w_out_lds[g * H + t];
        wc1[g] = w_out_lds[g * H + t + 64];
        wob[g] = W_out_b[(size_t)b * G + g];   // uniform -> scalar load
    }

    // ---- neuron state ----
    float hv0 = hv_in[(size_t)b * H + t],      hv1 = hv_in[(size_t)b * H + t + 64];
    float hu0 = hu_in[(size_t)b * H + t],      hu1 = hu_in[(size_t)b * H + t + 64];
    float hr0 = hrate_in[(size_t)b * H + t],   hr1 = hrate_in[(size_t)b * H + t + 64];
    float vv[G], vu[G], vr[G];
    #pragma unroll
    for (int g = 0; g < G; ++g) {
        vv[g] = vv_in[(size_t)b * G + g];      // uniform -> scalar loads
        vu[g] = vu_in[(size_t)b * G + g];
        vr[g] = vrate_in[(size_t)b * G + g];
    }

    // ---- prefetch all 20x2 noise values (coalesced) ----
    float nz0[S], nz1[S];
    #pragma unroll
    for (int s = 0; s < S; ++s) {
        nz0[s] = noise[((size_t)s * nB + b) * H + t];
        nz1[s] = noise[((size_t)s * nB + b) * H + t + 64];
    }

    float hsp0 = 0.0f, hsp1 = 0.0f;
    float vals[G] = {0.f, 0.f, 0.f, 0.f};  // last step's raw I_out == values

    // ---- 20 substeps: pure register/shuffle, zero barriers ----
    #pragma unroll
    for (int s = 0; s < S; ++s) {
        {   // hidden neuron h0
            float I  = Iin0 + 0.3f * nz0[s];
            float vn = hv0 + (0.04f * hv0 * hv0 + 5.0f * hv0 + 140.0f - hu0 + I);
            float un = hu0 + 0.02f * (0.2f * hv0 - hu0);
            float sp = (vn >= 30.0f) ? 1.0f : 0.0f;
            hv0 = (sp > 0.0f) ? -65.0f : vn;
            hu0 = un + sp * 8.0f;
            hr0 = 0.9f * hr0 + 0.1f * sp;
            hsp0 += sp;
        }
        {   // hidden neuron h1
            float I  = Iin1 + 0.3f * nz1[s];
            float vn = hv1 + (0.04f * hv1 * hv1 + 5.0f * hv1 + 140.0f - hu1 + I);
            float un = hu1 + 0.02f * (0.2f * hv1 - hu1);
            float sp = (vn >= 30.0f) ? 1.0f : 0.0f;
            hv1 = (sp > 0.0f) ? -65.0f : vn;
            hu1 = un + sp * 8.0f;
            hr1 = 0.9f * hr1 + 0.1f * sp;
            hsp1 += sp;
        }

        // I_out[g] = sum_h w[g,h]*hr[h]: per-lane partials + 4-way butterfly
        float p0 = wc0[0] * hr0 + wc1[0] * hr1;
        float p1 = wc0[1] * hr0 + wc1[1] * hr1;
        float p2 = wc0[2] * hr0 + wc1[2] * hr1;
        float p3 = wc0[3] * hr0 + wc1[3] * hr1;
        #pragma unroll
        for (int m = 32; m >= 1; m >>= 1) {
            p0 += __shfl_xor(p0, m, 64);
            p1 += __shfl_xor(p1, m, 64);
            p2 += __shfl_xor(p2, m, 64);
            p3 += __shfl_xor(p3, m, 64);
        }
        vals[0] = p0 + wob[0];
        vals[1] = p1 + wob[1];
        vals[2] = p2 + wob[2];
        vals[3] = p3 + wob[3];

        // output Izhikevich step, redundantly in all lanes (SIMT-free)
        float m4 = 0.25f * (fabsf(vals[0]) + fabsf(vals[1])
                          + fabsf(vals[2]) + fabsf(vals[3]));
        float onorm = 4.0f / (m4 + 1e-8f);
        #pragma unroll
        for (int g = 0; g < G; ++g) {
            float Io = vals[g] * onorm;
            float vn = vv[g] + (0.04f * vv[g] * vv[g] + 5.0f * vv[g] + 140.0f - vu[g] + Io);
            float un = vu[g] + 0.02f * (0.2f * vv[g] - vu[g]);
            float sp = (vn >= 30.0f) ? 1.0f : 0.0f;
            vv[g] = (sp > 0.0f) ? -65.0f : vn;
            vu[g] = un + sp * 8.0f;
            vr[g] = 0.9f * vr[g] + 0.1f * sp;
        }
    }

    // ---- share final hrate via LDS (in-wave, no barrier cost) ----
    hrate_lds[t] = hr0;
    hrate_lds[t + 64] = hr1;
    __syncthreads();

    // values: last step's raw I_out (reference's final einsum uses the same
    // final hrate as step 19's I_out, so it is identical)
    if (t < G) {
        float v = (t == 0) ? vals[0] : (t == 1) ? vals[1] : (t == 2) ? vals[2] : vals[3];
        out_values[(size_t)b * G + t] = v;
    }

    // hidden_active = fraction of the 128 neurons that spiked at least once
    unsigned long long mb0 = __ballot(hsp0 > 0.0f);
    unsigned long long mb1 = __ballot(hsp1 > 0.0f);
    float hidden = (float)(__popcll(mb0) + __popcll(mb1)) * (1.0f / 128.0f);

    int gl = goal[b];
    float Vnow  = (gl == 0) ? vals[0] : (gl == 1) ? vals[1] : (gl == 2) ? vals[2] : vals[3];
    float Vprev = prev_values[(size_t)b * G + prev_goal[b]];
    float td = reward[b] + 0.95f * Vnow - Vprev;
    if (t == 0) {
        out_td[b]     = td;
        out_hidden[b] = hidden;
    }

    const float scale = 1e-3f * td * DA[b];
    const bool  upd   = fabsf(td) > 1e-3f;

    // ---- elig_in / W_in update: 512 float4s, coalesced, W_in from LDS ----
    {
        const float4* ei4 = (const float4*)(elig_in + (size_t)b * (H * F));
        float4* oW = (float4*)(out_Win + (size_t)b * (H * F));
        float4* oE = (float4*)(out_ein + (size_t)b * (H * F));
        float4 pf = ((const float4*)pf_lds)[t & 3];  // same f-quad for all k
        #pragma unroll
        for (int k = 0; k < 8; ++k) {
            int q = t + 64 * k;
            float4 e  = ei4[q];
            float  hrv = hrate_lds[q >> 2];
            float4 en;
            en.x = 0.9f * e.x + hrv * pf.x;
            en.y = 0.9f * e.y + hrv * pf.y;
            en.z = 0.9f * e.z + hrv * pf.z;
            en.w = 0.9f * e.w + hrv * pf.w;
            oE[q] = en;
            float4 w = wl4[q];
            float4 wn;
            if (upd) {
                wn.x = clip3(w.x + scale * en.x);
                wn.y = clip3(w.y + scale * en.y);
                wn.z = clip3(w.z + scale * en.z);
                wn.w = clip3(w.w + scale * en.w);
            } else {
                wn = w;
            }
            oW[q] = wn;
        }
    }

    // ---- elig_out / W_out update: 128 float4s ----
    {
        const float4* eo4 = (const float4*)(elig_out + (size_t)b * (G * H));
        float4* oW = (float4*)(out_Wout + (size_t)b * (G * H));
        float4* oE = (float4*)(out_eout + (size_t)b * (G * H));
        #pragma unroll
        for (int k = 0; k < 2; ++k) {
            int q  = t + 64 * k;
            int gg = q >> 5;
            float vrv = (gg == 0) ? vr[0] : (gg == 1) ? vr[1] : (gg == 2) ? vr[2] : vr[3];
            float4 hq = ((const float4*)hrate_lds)[q & 31];
            float4 e  = eo4[q];
            float4 en;
            en.x = 0.9f * e.x + vrv * hq.x;
            en.y = 0.9f * e.y + vrv * hq.y;
            en.z = 0.9f * e.z + vrv * hq.z;
            en.w = 0.9f * e.w + vrv * hq.w;
            oE[q] = en;
            float4 w = ((const float4*)w_out_lds)[q];
            float4 wn;
            if (upd) {
                wn.x = clip3(w.x + scale * en.x);
                wn.y = clip3(w.y + scale * en.y);
                wn.z = clip3(w.z + scale * en.z);
                wn.w = clip3(w.w + scale * en.w);
            } else {
                wn = w;
            }
            oW[q] = wn;
        }
    }
}

} // namespace

extern "C" void kernel_launch(void* const* d_in, const int* in_sizes, int n_in,
                              void* d_out, int out_size, void* d_ws, size_t ws_size,
                              hipStream_t stream) {
    const int nB = in_sizes[0];          // 8192

    float* out        = (float*)d_out;   // outputs concatenated flat
    float* out_values = out;
    float* out_td     = out_values + (size_t)nB * G;
    float* out_hidden = out_td + nB;
    float* out_Win    = out_hidden + nB;
    float* out_Wout   = out_Win + (size_t)nB * H * F;
    float* out_ein    = out_Wout + (size_t)nB * G * H;
    float* out_eout   = out_ein + (size_t)nB * H * F;

    spiking_critic_kernel<<<dim3(nB), dim3(64), 0, stream>>>(
        (const float*)d_in[0],  (const float*)d_in[1],  (const float*)d_in[2],
        (const int*)  d_in[3],  (const int*)  d_in[4],
        (const float*)d_in[5],  (const float*)d_in[6],  (const float*)d_in[7],
        (const float*)d_in[8],  (const float*)d_in[9],  (const float*)d_in[10],
        (const float*)d_in[11], (const float*)d_in[12], (const float*)d_in[13],
        (const float*)d_in[14], (const float*)d_in[15], (const float*)d_in[16],
        (const float*)d_in[17], (const float*)d_in[18], (const float*)d_in[19],
        (const float*)d_in[20], (const float*)d_in[21], (const float*)d_in[22],
        (const float*)d_in[23],
        out_values, out_td, out_hidden, out_Win, out_Wout, out_ein, out_eout,
        nB);
}